// Round 3
// baseline (446.471 us; speedup 1.0000x reference)
//
#include <hip/hip_runtime.h>
#include <hip/hip_bf16.h>

#define BB  2048
#define TT  128
#define DD  128
#define HH1 128
#define GG1 512
#define HH2 64
#define GG2 256
#define OO  64

typedef __attribute__((ext_vector_type(8))) short  short8;
typedef __attribute__((ext_vector_type(4))) float  floatx4;

// Pin a value into VGPRs: opaque asm makes rematerializing the load illegal.
#define PIN(x) asm volatile("" : "+v"(x))

// ws byte offsets
#define OFF_WHH1 0            // bf16 [512][128]  (exp2-prescaled)
#define OFF_WIH1 131072       // bf16 [512][128]  (exp2-prescaled)
#define OFF_WIH2 262144       // bf16 [256][128]  (exp2-prescaled)
#define OFF_WHH2 327680       // bf16 [256][64]   (exp2-prescaled)
#define OFF_B1   360448       // f32 [512]  (b_ih1+b_hh1)*scale
#define OFF_B2   362496       // f32 [256]  (b_ih2+b_hh2)*scale
#define OFF_XBF  524288       // bf16 [2048][128][128]  x cast to bf16
#define OFF_H1S  67633152     // bf16 [2048][128][128]  layer-1 hidden seq

#define L2E      1.44269504088896340736f
#define TWO_L2E  2.88539008177792681472f

__device__ __forceinline__ short f2bf(float f) {
  unsigned u = __float_as_uint(f);
  unsigned r = (u + 0x7FFFu + ((u >> 16) & 1u)) >> 16;
  return (short)r;
}
__device__ __forceinline__ float exp2_f(float x) {
  float r; asm("v_exp_f32 %0, %1" : "=v"(r) : "v"(x)); return r;
}
// y is pre-scaled: y = -x*log2(e)   -> sigmoid(x)
__device__ __forceinline__ float sigm2(float y) {
  return __builtin_amdgcn_rcpf(1.0f + exp2_f(y));
}
// y is pre-scaled: y = 2x*log2(e)   -> tanh(x)
__device__ __forceinline__ float tanh2(float y) {
  return fmaf(-2.0f, __builtin_amdgcn_rcpf(1.0f + exp2_f(y)), 1.0f);
}

// Barrier that drains ONLY LDS ops (lgkmcnt). Global stores (h1s, never read
// here) and global prefetch loads (vmcnt-waited at their use) stay in flight.
__device__ __forceinline__ void lds_barrier() {
  asm volatile("s_waitcnt lgkmcnt(0)" ::: "memory");
  __builtin_amdgcn_s_barrier();
  asm volatile("" ::: "memory");
}

// ---------------- prep: bf16 weight conversion + combined biases ----------------
// Weights/biases for sigmoid gates (i,f,o) scaled by -log2(e); tanh gate (g)
// scaled by +2*log2(e): cell then uses raw v_exp_f32 (exp2) with no mul.
__global__ void k_prep(const float* __restrict__ wih1, const float* __restrict__ whh1,
                       const float* __restrict__ bih1, const float* __restrict__ bhh1,
                       const float* __restrict__ wih2, const float* __restrict__ whh2,
                       const float* __restrict__ bih2, const float* __restrict__ bhh2,
                       char* __restrict__ ws) {
  short* WHH1 = (short*)(ws + OFF_WHH1);
  short* WIH1 = (short*)(ws + OFF_WIH1);
  short* WIH2 = (short*)(ws + OFF_WIH2);
  short* WHH2 = (short*)(ws + OFF_WHH2);
  float* B1 = (float*)(ws + OFF_B1);
  float* B2 = (float*)(ws + OFF_B2);
  int idx = blockIdx.x * blockDim.x + threadIdx.x;
  int stride = gridDim.x * blockDim.x;
  const float SCI = -L2E, SCG = TWO_L2E;
  for (int i = idx; i < GG1 * DD; i += stride) {
    int g = (i >> 7) >> 7;                      // row/128 = gate
    float s = (g == 2) ? SCG : SCI;
    WIH1[i] = f2bf(wih1[i] * s); WHH1[i] = f2bf(whh1[i] * s);
  }
  for (int i = idx; i < GG2 * HH1; i += stride) {
    int g = (i >> 7) >> 6; float s = (g == 2) ? SCG : SCI;
    WIH2[i] = f2bf(wih2[i] * s);
  }
  for (int i = idx; i < GG2 * HH2; i += stride) {
    int g = (i >> 6) >> 6; float s = (g == 2) ? SCG : SCI;
    WHH2[i] = f2bf(whh2[i] * s);
  }
  for (int i = idx; i < GG1; i += stride) {
    float s = ((i >> 7) == 2) ? SCG : SCI;
    B1[i] = (bih1[i] + bhh1[i]) * s;
  }
  for (int i = idx; i < GG2; i += stride) {
    float s = ((i >> 6) == 2) ? SCG : SCI;
    B2[i] = (bih2[i] + bhh2[i]) * s;
  }
}

// ---------------- xcast: x fp32 -> bf16, 8 elems/thread ----------------
__global__ __launch_bounds__(256) void k_xcast(const float* __restrict__ x,
                                               short* __restrict__ xbf) {
  size_t i = ((size_t)blockIdx.x * 256 + threadIdx.x) * 8;
  float4 a = *(const float4*)&x[i];
  float4 b = *(const float4*)&x[i + 4];
  short8 o;
  o[0] = f2bf(a.x); o[1] = f2bf(a.y); o[2] = f2bf(a.z); o[3] = f2bf(a.w);
  o[4] = f2bf(b.x); o[5] = f2bf(b.y); o[6] = f2bf(b.z); o[7] = f2bf(b.w);
  *(short8*)&xbf[i] = o;
}

// ---------------- rec1f: fused input-proj + recurrence, layer 1 ----------------
// 8 rows/block, grid 256, 8 waves, 2 blocks/CU. Wave wv owns hidden cols
// wv*16..+15; gate tiles n = {0,128,256,384}+hc -> i,f,g,o of a cell in one
// thread's 4 accs; cell from registers, 1 lgkm-only barrier/t. Input proj of
// t+1 pipelined into step t. Bias lives in floatx4 consumed as MFMA C (no
// per-step movs); ax uses ping-pong register sets (no copies).
__global__ __launch_bounds__(512, 2) void k_rec1f(const char* __restrict__ ws,
                                                  short* __restrict__ h1s) {
  __shared__ short hbds[2][16 * 136];   // bf16 h double-buffer, rows 8..15 stay 0
  const short* WHH = (const short*)(ws + OFF_WHH1);
  const short* WIH = (const short*)(ws + OFF_WIH1);
  const short* XBF = (const short*)(ws + OFF_XBF);
  const float* B1 = (const float*)(ws + OFF_B1);
  const int lane = threadIdx.x & 63;
  const int wv = threadIdx.x >> 6;          // 0..7
  const int col = lane & 15, quad = lane >> 4;
  const int hc = wv * 16 + col;             // hidden col owned by this thread
  const int r0 = blockIdx.x * 8;

  short8 wh[4][4], wx[4][4];
#pragma unroll
  for (int gt = 0; gt < 4; ++gt)
#pragma unroll
    for (int kk = 0; kk < 4; ++kk) {
      wh[gt][kk] = *(const short8*)&WHH[(gt * 128 + hc) * HH1 + kk * 32 + quad * 8];
      wx[gt][kk] = *(const short8*)&WIH[(gt * 128 + hc) * DD + kk * 32 + quad * 8];
      PIN(wh[gt][kk]);
      PIN(wx[gt][kk]);
    }
  floatx4 BIASV[4];
#pragma unroll
  for (int gt = 0; gt < 4; ++gt) {
    float b = B1[gt * 128 + hc];
    BIASV[gt] = (floatx4){b, b, b, b};
    PIN(BIASV[gt]);
  }

  for (int i = threadIdx.x; i < 2 * 16 * 136; i += 512) ((short*)hbds)[i] = 0;

  const bool aload = (col < 8);
  const short* xbase = XBF + (size_t)(r0 + (col & 7)) * TT * DD;
  const short8 zz = {0, 0, 0, 0, 0, 0, 0, 0};
  short8 axA[4], axB[4];
  floatx4 accA[4], accB[4];

  // prologue: accA = bias + x_0*Wx ; axA = x_1 ; axB = 0
  {
    short8 ax0[4];
#pragma unroll
    for (int kk = 0; kk < 4; ++kk)
      ax0[kk] = aload ? *(const short8*)&xbase[kk * 32 + quad * 8] : zz;
#pragma unroll
    for (int gt = 0; gt < 4; ++gt)
      accA[gt] = __builtin_amdgcn_mfma_f32_16x16x32_bf16(ax0[0], wx[gt][0], BIASV[gt], 0, 0, 0);
#pragma unroll
    for (int kk = 1; kk < 4; ++kk)
#pragma unroll
      for (int gt = 0; gt < 4; ++gt)
        accA[gt] = __builtin_amdgcn_mfma_f32_16x16x32_bf16(ax0[kk], wx[gt][kk], accA[gt], 0, 0, 0);
  }
#pragma unroll
  for (int kk = 0; kk < 4; ++kk) {
    axA[kk] = aload ? *(const short8*)&xbase[DD + kk * 32 + quad * 8] : zz;
    axB[kk] = zz;
  }

  // rows covered after shfl rebalance: quad0->{0,1} quad1->{4,5} quad2->{2,3} quad3->{6,7}
  const int row0 = (quad & 1) * 4 + (quad >> 1) * 2;
  float c0 = 0.f, c1 = 0.f;
  __syncthreads();   // full barrier once (covers hbds zero-init)

  auto step = [&](int t, short* rbuf, short* wbuf, floatx4* A, floatx4* Bn,
                  short8* axC, short8* axP) {
    // prefetch x_{t+2} into the set consumed two steps from now
    if (aload && t + 2 < TT) {
#pragma unroll
      for (int kk = 0; kk < 4; ++kk)
        axP[kk] = *(const short8*)&xbase[(t + 2) * DD + kk * 32 + quad * 8];
    }
    // recurrence: A += h_t * Whh
    short8 ah[4];
#pragma unroll
    for (int kk = 0; kk < 4; ++kk)
      ah[kk] = *(const short8*)&rbuf[col * 136 + kk * 32 + quad * 8];
#pragma unroll
    for (int kk = 0; kk < 4; ++kk)
#pragma unroll
      for (int gt = 0; gt < 4; ++gt)
        A[gt] = __builtin_amdgcn_mfma_f32_16x16x32_bf16(ah[kk], wh[gt][kk], A[gt], 0, 0, 0);
    // pipelined input projection for t+1 (bias as MFMA C input, no movs)
#pragma unroll
    for (int gt = 0; gt < 4; ++gt)
      Bn[gt] = __builtin_amdgcn_mfma_f32_16x16x32_bf16(axC[0], wx[gt][0], BIASV[gt], 0, 0, 0);
#pragma unroll
    for (int kk = 1; kk < 4; ++kk)
#pragma unroll
      for (int gt = 0; gt < 4; ++gt)
        Bn[gt] = __builtin_amdgcn_mfma_f32_16x16x32_bf16(axC[kk], wx[gt][kk], Bn[gt], 0, 0, 0);

    // rebalance rows 2,3 / 6,7 onto quads 2,3 so all 64 lanes do 2 cells
    float g0[4], g1[4];
#pragma unroll
    for (int gt = 0; gt < 4; ++gt) {
      float v2 = __shfl_xor(A[gt][2], 32);
      float v3 = __shfl_xor(A[gt][3], 32);
      g0[gt] = (quad < 2) ? A[gt][0] : v2;
      g1[gt] = (quad < 2) ? A[gt][1] : v3;
    }
    {
      float i0 = sigm2(g0[0]), f0 = sigm2(g0[1]), gg0 = tanh2(g0[2]), o0 = sigm2(g0[3]);
      c0 = fmaf(f0, c0, i0 * gg0);
      float hA = o0 * tanh2(c0 * TWO_L2E);
      float i1 = sigm2(g1[0]), f1 = sigm2(g1[1]), gg1 = tanh2(g1[2]), o1 = sigm2(g1[3]);
      c1 = fmaf(f1, c1, i1 * gg1);
      float hB = o1 * tanh2(c1 * TWO_L2E);
      short ha = f2bf(hA), hbv = f2bf(hB);
      wbuf[(row0)     * 136 + hc] = ha;
      wbuf[(row0 + 1) * 136 + hc] = hbv;
      h1s[((size_t)(r0 + row0)     * TT + t) * HH1 + hc] = ha;
      h1s[((size_t)(r0 + row0 + 1) * TT + t) * HH1 + hc] = hbv;
    }
    lds_barrier();
  };

  for (int t = 0; t < TT; t += 2) {
    step(t,     &hbds[0][0], &hbds[1][0], accA, accB, axA, axB);
    step(t + 1, &hbds[1][0], &hbds[0][0], accB, accA, axB, axA);
  }
}

// ---------------- rec2r: layer 2 register-cell + dense head ----------------
// 4 rows/block, grid 512 (2 blocks/CU = 2 barrier domains), 4 waves. Wave wv
// owns hidden cols wv*16..+15 with ALL 4 gate tiles (n = gt*64+hc): i,f,g,o
// in one thread's accs -> no gsm round-trip, 1 lgkm barrier/step. Real batch
// rows 0..3 land on quads 0 (rows 0,1) and 2 (rows 2,3) after the rec1f-style
// shfl rebalance; quads 1,3 compute bias-only garbage that is never stored.
__global__ __launch_bounds__(256, 2) void k_rec2r(const char* __restrict__ ws,
                                                  const short* __restrict__ h1s,
                                                  const float* __restrict__ wd,
                                                  const float* __restrict__ bd,
                                                  float* __restrict__ out) {
  __shared__ short hbds[2][16 * 72];  // bf16 h2 double-buffer, rows 4..15 stay 0
  __shared__ float h2f[4 * HH2];      // final fp32 h2
  const short* WHH = (const short*)(ws + OFF_WHH2);
  const short* WIH = (const short*)(ws + OFF_WIH2);
  const float* B2 = (const float*)(ws + OFF_B2);
  const int lane = threadIdx.x & 63;
  const int wv = threadIdx.x >> 6;    // 0..3
  const int col = lane & 15, quad = lane >> 4;
  const int hc = wv * 16 + col;       // hidden col 0..63
  const int r0 = blockIdx.x * 4;

  short8 wh[4][2], wx[4][4];
#pragma unroll
  for (int gt = 0; gt < 4; ++gt) {
#pragma unroll
    for (int kk = 0; kk < 2; ++kk) {
      wh[gt][kk] = *(const short8*)&WHH[(gt * 64 + hc) * HH2 + kk * 32 + quad * 8];
      PIN(wh[gt][kk]);
    }
#pragma unroll
    for (int kk = 0; kk < 4; ++kk) {
      wx[gt][kk] = *(const short8*)&WIH[(gt * 64 + hc) * HH1 + kk * 32 + quad * 8];
      PIN(wx[gt][kk]);
    }
  }
  floatx4 BIASV[4];
#pragma unroll
  for (int gt = 0; gt < 4; ++gt) {
    float b = B2[gt * 64 + hc];
    BIASV[gt] = (floatx4){b, b, b, b};
    PIN(BIASV[gt]);
  }

  for (int i = threadIdx.x; i < 2 * 16 * 72; i += 256) ((short*)hbds)[i] = 0;

  const bool aload = (col < 4);
  const short* h1base = h1s + (size_t)(r0 + (col & 3)) * TT * HH1;
  const short8 zz = {0, 0, 0, 0, 0, 0, 0, 0};
  short8 axA[4], axB[4];
  floatx4 accA[4], accB[4];

  // prologue: accA = bias + h1_0*Wih2 ; axA = h1_1 ; axB = 0
  {
    short8 ax0[4];
#pragma unroll
    for (int kk = 0; kk < 4; ++kk)
      ax0[kk] = aload ? *(const short8*)&h1base[kk * 32 + quad * 8] : zz;
#pragma unroll
    for (int gt = 0; gt < 4; ++gt)
      accA[gt] = __builtin_amdgcn_mfma_f32_16x16x32_bf16(ax0[0], wx[gt][0], BIASV[gt], 0, 0, 0);
#pragma unroll
    for (int kk = 1; kk < 4; ++kk)
#pragma unroll
      for (int gt = 0; gt < 4; ++gt)
        accA[gt] = __builtin_amdgcn_mfma_f32_16x16x32_bf16(ax0[kk], wx[gt][kk], accA[gt], 0, 0, 0);
  }
#pragma unroll
  for (int kk = 0; kk < 4; ++kk) {
    axA[kk] = aload ? *(const short8*)&h1base[HH1 + kk * 32 + quad * 8] : zz;
    axB[kk] = zz;
  }

  const int row0 = (quad & 1) * 4 + (quad >> 1) * 2;  // quads 0,2 -> rows {0,1},{2,3}
  const bool realq = ((quad & 1) == 0);
  float c0 = 0.f, c1 = 0.f;
  __syncthreads();   // covers hbds zero-init

  auto step = [&](int t, short* rbuf, short* wbuf, floatx4* A, floatx4* Bn,
                  short8* axC, short8* axP) {
    // prefetch h1_{t+2}
    if (aload && t + 2 < TT) {
#pragma unroll
      for (int kk = 0; kk < 4; ++kk)
        axP[kk] = *(const short8*)&h1base[(t + 2) * HH1 + kk * 32 + quad * 8];
    }
    // recurrence: A += h2_t * Whh2  (K=64)
    short8 ah[2];
#pragma unroll
    for (int kk = 0; kk < 2; ++kk)
      ah[kk] = *(const short8*)&rbuf[col * 72 + kk * 32 + quad * 8];
#pragma unroll
    for (int kk = 0; kk < 2; ++kk)
#pragma unroll
      for (int gt = 0; gt < 4; ++gt)
        A[gt] = __builtin_amdgcn_mfma_f32_16x16x32_bf16(ah[kk], wh[gt][kk], A[gt], 0, 0, 0);
    // pipelined input projection for t+1 (K=128)
#pragma unroll
    for (int gt = 0; gt < 4; ++gt)
      Bn[gt] = __builtin_amdgcn_mfma_f32_16x16x32_bf16(axC[0], wx[gt][0], BIASV[gt], 0, 0, 0);
#pragma unroll
    for (int kk = 1; kk < 4; ++kk)
#pragma unroll
      for (int gt = 0; gt < 4; ++gt)
        Bn[gt] = __builtin_amdgcn_mfma_f32_16x16x32_bf16(axC[kk], wx[gt][kk], Bn[gt], 0, 0, 0);

    // rebalance (same as rec1f); quads 1,3 hold zero-row garbage, not stored
    float g0[4], g1[4];
#pragma unroll
    for (int gt = 0; gt < 4; ++gt) {
      float v2 = __shfl_xor(A[gt][2], 32);
      float v3 = __shfl_xor(A[gt][3], 32);
      g0[gt] = (quad < 2) ? A[gt][0] : v2;
      g1[gt] = (quad < 2) ? A[gt][1] : v3;
    }
    {
      float i0 = sigm2(g0[0]), f0 = sigm2(g0[1]), gg0 = tanh2(g0[2]), o0 = sigm2(g0[3]);
      c0 = fmaf(f0, c0, i0 * gg0);
      float hA = o0 * tanh2(c0 * TWO_L2E);
      float i1 = sigm2(g1[0]), f1 = sigm2(g1[1]), gg1 = tanh2(g1[2]), o1 = sigm2(g1[3]);
      c1 = fmaf(f1, c1, i1 * gg1);
      float hB = o1 * tanh2(c1 * TWO_L2E);
      if (realq) {
        wbuf[(row0)     * 72 + hc] = f2bf(hA);
        wbuf[(row0 + 1) * 72 + hc] = f2bf(hB);
        if (t == TT - 1) {
          h2f[(row0)     * HH2 + hc] = hA;
          h2f[(row0 + 1) * HH2 + hc] = hB;
        }
      }
    }
    lds_barrier();
  };

  for (int t = 0; t < TT; t += 2) {
    step(t,     &hbds[0][0], &hbds[1][0], accA, accB, axA, axB);
    step(t + 1, &hbds[1][0], &hbds[0][0], accB, accA, axB, axA);
  }

  // dense head (fp32): 4 rows x 64 outs = 256 threads, 1 each
  {
    const int o = threadIdx.x & 63;
    const int r = threadIdx.x >> 6;   // 0..3
    float acc = bd[o];
    for (int k = 0; k < HH2; ++k)
      acc = fmaf(h2f[r * HH2 + k], wd[o * HH2 + k], acc);
    out[(size_t)(r0 + r) * OO + o] = fmaxf(acc, 0.f);
  }
}

extern "C" void kernel_launch(void* const* d_in, const int* in_sizes, int n_in,
                              void* d_out, int out_size, void* d_ws, size_t ws_size,
                              hipStream_t stream) {
  const float* x       = (const float*)d_in[0];
  const float* w_ih1   = (const float*)d_in[1];
  const float* w_hh1   = (const float*)d_in[2];
  const float* b_ih1   = (const float*)d_in[3];
  const float* b_hh1   = (const float*)d_in[4];
  const float* w_ih2   = (const float*)d_in[5];
  const float* w_hh2   = (const float*)d_in[6];
  const float* b_ih2   = (const float*)d_in[7];
  const float* b_hh2   = (const float*)d_in[8];
  const float* w_dense = (const float*)d_in[9];
  const float* b_dense = (const float*)d_in[10];
  char* ws = (char*)d_ws;
  short* xbf = (short*)(ws + OFF_XBF);
  short* h1s = (short*)(ws + OFF_H1S);
  float* out = (float*)d_out;

  hipLaunchKernelGGL(k_prep, dim3(256), dim3(256), 0, stream,
                     w_ih1, w_hh1, b_ih1, b_hh1, w_ih2, w_hh2, b_ih2, b_hh2, ws);
  hipLaunchKernelGGL(k_xcast, dim3((BB * TT * DD) / (256 * 8)), dim3(256), 0, stream, x, xbf);
  hipLaunchKernelGGL(k_rec1f, dim3(BB / 8), dim3(512), 0, stream, ws, h1s);
  hipLaunchKernelGGL(k_rec2r, dim3(BB / 4), dim3(256), 0, stream, ws, h1s, w_dense, b_dense, out);
}